// Round 1
// baseline (795.824 us; speedup 1.0000x reference)
//
#include <hip/hip_runtime.h>

// ---------------------------------------------------------------------------
// SPDBatchNormMean forward, B=8192, n=64, fp32. Eigendecomp-free:
//   G0 = mean(x); Gs/Gis = G0^{±1/2} (Newton-Schulz); M = mean log(Gis x Gis)
//   (deg-18 Chebyshev on [0.3,4.0]); G1 = Gs expm(M) Gs; Gis1 = G1^{-1/2};
//   C = Bs Gis1 (Bs = bias^{1/2}); out = C x C^T.
// Round 3: occupancy restructure.
//   - k3/k5: 256-thread blocks (one matrix chain each), grid 1024, 8 mats per
//     block. LDS 32.5 KB/block -> 4 blocks/CU co-resident (was 1 block/CU at
//     65 KB): 4 independent Chebyshev chains per CU overlap VALU and MFMA
//     phases across blocks. Partials for k3/k1 staged in `out` (dead until
//     k5), since 1024 slots no longer fit the 4 MB workspace.
//   - two-stage partial reduce (64 blocks -> 4 blocks) instead of 4-block
//     single stage.
//   - f2bf via hardware (__bf16) cast (RNE, bit-identical to the manual
//     round-nearest-even) -> compiler can emit v_cvt_pk_bf16_f32.
// ---------------------------------------------------------------------------

#define BATCH 8192
#define NMAT 64
#define MSIZE 4096
#define NBLK_RED 512
#define NBLK_K3 1024
#define MATS_K3 8
#define NBLK_K5 1024
#define MATS_K5 8
#define DEG 18
#define CHEB_LO 0.30f
#define CHEB_HI 4.00f
#define NS_ITERS_MEAN 10
#define NS_ITERS_BIAS 12
#define GSTR 520 /* padded k-group stride (65*8 elems, 16B-aligned) */

// workspace layout (floats): only the 6 small matrices now (96 KB).
#define G_OFF 0
#define BS_OFF (G_OFF + MSIZE)
#define GS_OFF (BS_OFF + MSIZE)
#define GIS_OFF (GS_OFF + MSIZE)
#define MBAR_OFF (GIS_OFF + MSIZE)
#define C_OFF (MBAR_OFF + MSIZE)
// scratch staged in `out` (128 MB, dead until k5): partial slots [0,1024),
// stage-1 reduce slots at [RED1_SLOT, RED1_SLOT+16).
#define RED1_SLOT 2048

typedef __attribute__((ext_vector_type(8))) short bf16x8;
typedef __attribute__((ext_vector_type(16))) float floatx16;
#define MFMA(a, b, c) __builtin_amdgcn_mfma_f32_32x32x16_bf16(a, b, c, 0, 0, 0)

__device__ __forceinline__ short f2bf(float x) {
  union {
    __bf16 b;
    short s;
  } u;
  u.b = (__bf16)x;  // hardware cvt, RNE (same as manual round-nearest-even)
  return u.s;
}
__device__ __forceinline__ float bf2f(short h) {
  return __uint_as_float(((unsigned)(unsigned short)h) << 16);
}

// Stage a row-major 64x64 fp32 global matrix M into hi/lo bf16 LDS arrays in
// B-layout holding M^T: arr(k,n) = M[n][k]. 256 threads (st), packed b64.
__device__ __forceinline__ void stageT(const float* __restrict__ src, short* ah,
                                       short* al, int st) {
#pragma unroll
  for (int jb = 0; jb < 4; ++jb) {
    int flat = jb * 1024 + st * 4;
    float4 v = *reinterpret_cast<const float4*>(src + flat);
    int i = flat >> 6;   // row of M
    int j0 = flat & 63;  // col base (multiple of 4)
    int addr = (j0 >> 3) * GSTR + i * 8 + (j0 & 7);
    short4 h, l;
    h.x = f2bf(v.x); l.x = f2bf(v.x - bf2f(h.x));
    h.y = f2bf(v.y); l.y = f2bf(v.y - bf2f(h.y));
    h.z = f2bf(v.z); l.z = f2bf(v.z - bf2f(h.z));
    h.w = f2bf(v.w); l.w = f2bf(v.w - bf2f(h.w));
    *reinterpret_cast<short4*>(ah + addr) = h;
    *reinterpret_cast<short4*>(al + addr) = l;
  }
}

// Fragment read: returns elements j=0..7 at k = kb*16 + q*8 + j, column n.
__device__ __forceinline__ bf16x8 readFrag(const short* a, int kb, int q,
                                           int n) {
  return *reinterpret_cast<const bf16x8*>(a + (kb * 2 + q) * GSTR + n * 8);
}

// Store 16 C/D-layout fp32 regs into B-layout array(s) as bf16 (direct:
// arr(k=row, n=col) = v). Packs 4 consecutive rows per b64 write.
__device__ __forceinline__ void storeChi(short* dh, const float* v, int R,
                                         int col, int q) {
#pragma unroll
  for (int g4 = 0; g4 < 4; ++g4) {
    int addr = (4 * R + g4) * GSTR + col * 8 + 4 * q;
    short4 h;
    h.x = f2bf(v[4 * g4 + 0]);
    h.y = f2bf(v[4 * g4 + 1]);
    h.z = f2bf(v[4 * g4 + 2]);
    h.w = f2bf(v[4 * g4 + 3]);
    *reinterpret_cast<short4*>(dh + addr) = h;
  }
}
__device__ __forceinline__ void storeChl(short* dh, short* dl, const float* v,
                                         int R, int col, int q) {
#pragma unroll
  for (int g4 = 0; g4 < 4; ++g4) {
    int addr = (4 * R + g4) * GSTR + col * 8 + 4 * q;
    short4 h, l;
    float a0 = v[4 * g4 + 0], a1 = v[4 * g4 + 1];
    float a2 = v[4 * g4 + 2], a3 = v[4 * g4 + 3];
    h.x = f2bf(a0); l.x = f2bf(a0 - bf2f(h.x));
    h.y = f2bf(a1); l.y = f2bf(a1 - bf2f(h.y));
    h.z = f2bf(a2); l.z = f2bf(a2 - bf2f(h.z));
    h.w = f2bf(a3); l.w = f2bf(a3 - bf2f(h.w));
    *reinterpret_cast<short4*>(dh + addr) = h;
    *reinterpret_cast<short4*>(dl + addr) = l;
  }
}

// ============================ vector-ALU helpers (k1/k2/k4) ================

__device__ __forceinline__ void mm64T(const float* __restrict__ A,
                                      const float* __restrict__ B, int rt,
                                      int ct, float p[4][4]) {
#pragma unroll
  for (int i = 0; i < 4; ++i)
#pragma unroll
    for (int j = 0; j < 4; ++j) p[i][j] = 0.0f;
#pragma unroll 4
  for (int k = 0; k < NMAT; ++k) {
    float4 a = *reinterpret_cast<const float4*>(A + k * NMAT + rt * 4);
    float4 b = *reinterpret_cast<const float4*>(B + k * NMAT + ct * 4);
    p[0][0] = fmaf(a.x, b.x, p[0][0]);
    p[0][1] = fmaf(a.x, b.y, p[0][1]);
    p[0][2] = fmaf(a.x, b.z, p[0][2]);
    p[0][3] = fmaf(a.x, b.w, p[0][3]);
    p[1][0] = fmaf(a.y, b.x, p[1][0]);
    p[1][1] = fmaf(a.y, b.y, p[1][1]);
    p[1][2] = fmaf(a.y, b.z, p[1][2]);
    p[1][3] = fmaf(a.y, b.w, p[1][3]);
    p[2][0] = fmaf(a.z, b.x, p[2][0]);
    p[2][1] = fmaf(a.z, b.y, p[2][1]);
    p[2][2] = fmaf(a.z, b.z, p[2][2]);
    p[2][3] = fmaf(a.z, b.w, p[2][3]);
    p[3][0] = fmaf(a.w, b.x, p[3][0]);
    p[3][1] = fmaf(a.w, b.y, p[3][1]);
    p[3][2] = fmaf(a.w, b.z, p[3][2]);
    p[3][3] = fmaf(a.w, b.w, p[3][3]);
  }
}

__device__ __forceinline__ void storeTile(float* dst, int rt, int ct,
                                          const float p[4][4]) {
#pragma unroll
  for (int i = 0; i < 4; ++i)
    *reinterpret_cast<float4*>(dst + (rt * 4 + i) * NMAT + ct * 4) =
        make_float4(p[i][0], p[i][1], p[i][2], p[i][3]);
}

__device__ __forceinline__ void loadMat(float* dst,
                                        const float* __restrict__ src,
                                        int tid) {
#pragma unroll
  for (int j = 0; j < 4; ++j)
    *reinterpret_cast<float4*>(dst + j * 1024 + tid * 4) =
        *reinterpret_cast<const float4*>(src + j * 1024 + tid * 4);
}

__device__ __forceinline__ float4 id4(int base) {
  return make_float4(((base + 0) % 65) == 0 ? 1.f : 0.f,
                     ((base + 1) % 65) == 0 ? 1.f : 0.f,
                     ((base + 2) % 65) == 0 ? 1.f : 0.f,
                     ((base + 3) % 65) == 0 ? 1.f : 0.f);
}

__device__ float block_ns(const float* lA, float* lY, float* lZ, float* lW,
                          float* red, int iters) {
  const int tid = threadIdx.x;
  const int rt = tid >> 4, ct = tid & 15;
  float ss = 0.0f;
#pragma unroll
  for (int j = 0; j < 4; ++j) {
    float4 v = *reinterpret_cast<const float4*>(lA + j * 1024 + tid * 4);
    ss += v.x * v.x + v.y * v.y + v.z * v.z + v.w * v.w;
  }
  red[tid] = ss;
  __syncthreads();
  for (int off = 128; off > 0; off >>= 1) {
    if (tid < off) red[tid] += red[tid + off];
    __syncthreads();
  }
  const float c = sqrtf(red[0] * 0.5f);
  const float rc = 1.0f / c;
#pragma unroll
  for (int j = 0; j < 4; ++j) {
    int base = j * 1024 + tid * 4;
    float4 v = *reinterpret_cast<const float4*>(lA + base);
    v.x *= rc;
    v.y *= rc;
    v.z *= rc;
    v.w *= rc;
    *reinterpret_cast<float4*>(lY + base) = v;
    *reinterpret_cast<float4*>(lZ + base) = id4(base);
  }
  __syncthreads();
  for (int it = 0; it < iters; ++it) {
    float p[4][4];
    mm64T(lZ, lY, rt, ct, p);
    float w[4][4];
#pragma unroll
    for (int i = 0; i < 4; ++i)
#pragma unroll
      for (int j = 0; j < 4; ++j)
        w[i][j] = ((rt * 4 + i) == (ct * 4 + j) ? 1.5f : 0.0f) - 0.5f * p[i][j];
    storeTile(lW, rt, ct, w);
    __syncthreads();
    float py[4][4], pz[4][4];
    mm64T(lY, lW, rt, ct, py);
    mm64T(lW, lZ, rt, ct, pz);
    __syncthreads();
    storeTile(lY, rt, ct, py);
    storeTile(lZ, rt, ct, pz);
    __syncthreads();
  }
  return c;
}

// K1: blocks [0,NBLK_RED) partial-sum x into `pg` (out scratch); block
// NBLK_RED does Bs = bias^{1/2}.
__global__ __launch_bounds__(256) void k1_mean_bias(
    const float* __restrict__ x, const float* __restrict__ bias,
    float* __restrict__ ws, float* __restrict__ pg) {
  const int tid = threadIdx.x;
  if (blockIdx.x < NBLK_RED) {
    float acc[16];
#pragma unroll
    for (int j = 0; j < 16; ++j) acc[j] = 0.f;
    for (int i = blockIdx.x; i < BATCH; i += NBLK_RED) {
      const float* src = x + (size_t)i * MSIZE;
#pragma unroll
      for (int j = 0; j < 4; ++j) {
        float4 v = *reinterpret_cast<const float4*>(src + j * 1024 + tid * 4);
        acc[j * 4 + 0] += v.x;
        acc[j * 4 + 1] += v.y;
        acc[j * 4 + 2] += v.z;
        acc[j * 4 + 3] += v.w;
      }
    }
    float* dst = pg + (size_t)blockIdx.x * MSIZE;
#pragma unroll
    for (int j = 0; j < 4; ++j)
      *reinterpret_cast<float4*>(dst + j * 1024 + tid * 4) = make_float4(
          acc[j * 4 + 0], acc[j * 4 + 1], acc[j * 4 + 2], acc[j * 4 + 3]);
  } else {
    __shared__ __align__(16) float lA[MSIZE], lY[MSIZE], lZ[MSIZE], lW[MSIZE];
    __shared__ float red[257];
    loadMat(lA, bias, tid);
    __syncthreads();
    float c = block_ns(lA, lY, lZ, lW, red, NS_ITERS_BIAS);
    float sc = sqrtf(c);
#pragma unroll
    for (int j = 0; j < 4; ++j) {
      int base = j * 1024 + tid * 4;
      float4 v = *reinterpret_cast<const float4*>(lY + base);
      v.x *= sc;
      v.y *= sc;
      v.z *= sc;
      v.w *= sc;
      *reinterpret_cast<float4*>(ws + BS_OFF + base) = v;
    }
  }
}

// Two-stage partial reduce. grid = (4, NP): block (bx, by) sums parts
// p = by, by+NP, ... for its 1 KB element range; writes slot `by` of dst.
// Second call with grid (4, 1) folds the NP intermediates.
__global__ __launch_bounds__(256) void k_reduce_parts(
    const float* __restrict__ src, float* __restrict__ dst, int nparts,
    float scale) {
  int e4 = blockIdx.x * 256 + threadIdx.x;
  float4 acc = make_float4(0.f, 0.f, 0.f, 0.f);
  for (int b = blockIdx.y; b < nparts; b += gridDim.y) {
    float4 v =
        *reinterpret_cast<const float4*>(src + (size_t)b * MSIZE + e4 * 4);
    acc.x += v.x;
    acc.y += v.y;
    acc.z += v.z;
    acc.w += v.w;
  }
  acc.x *= scale;
  acc.y *= scale;
  acc.z *= scale;
  acc.w *= scale;
  *reinterpret_cast<float4*>(dst + (size_t)blockIdx.y * MSIZE + e4 * 4) = acc;
}

__global__ __launch_bounds__(256) void k2_mean_ns(float* __restrict__ ws) {
  __shared__ __align__(16) float lA[MSIZE], lY[MSIZE], lZ[MSIZE], lW[MSIZE];
  __shared__ float red[257];
  const int tid = threadIdx.x;
  loadMat(lA, ws + G_OFF, tid);
  __syncthreads();
  float c = block_ns(lA, lY, lZ, lW, red, NS_ITERS_MEAN);
  float sc = sqrtf(c), rs = 1.0f / sqrtf(c);
#pragma unroll
  for (int j = 0; j < 4; ++j) {
    int base = j * 1024 + tid * 4;
    float4 y = *reinterpret_cast<const float4*>(lY + base);
    float4 z = *reinterpret_cast<const float4*>(lZ + base);
    *reinterpret_cast<float4*>(ws + GS_OFF + base) =
        make_float4(y.x * sc, y.y * sc, y.z * sc, y.w * sc);
    *reinterpret_cast<float4*>(ws + GIS_OFF + base) =
        make_float4(z.x * rs, z.y * rs, z.z * rs, z.w * rs);
  }
}

// ============================ K3: MFMA Chebyshev log-sum ====================
// 256 threads = 4 waves, one matrix chain at a time, 8 mats/block, grid 1024.
// 32.5 KB LDS -> 4 blocks/CU: 4 independent chains per CU overlap VALU/MFMA.
__global__ __launch_bounds__(256) void k3_logsum_mfma(
    const float* __restrict__ x, const float* __restrict__ ws,
    float* __restrict__ pm) {
  __shared__ __align__(16) short SH[4][GSTR * 8];
  const int tid = threadIdx.x;
  const int w4 = tid >> 6;
  const int R = w4 >> 1, Cb = w4 & 1;
  const int lane = tid & 63;
  const int ln = lane & 31, q = lane >> 5;
  const int col = 32 * Cb + ln;
  short* Ah = SH[0];
  short* Al = SH[1];
  short* Bh = SH[2];
  short* Bl = SH[3];

  const float m = 0.5f * (CHEB_LO + CHEB_HI), hh = 0.5f * (CHEB_HI - CHEB_LO);
  const float invh = 1.0f / hh;
  const float beta = hh / m;
  const float zeta = (1.0f - sqrtf(1.0f - beta * beta)) / beta;
  const float a0 = logf(m) - log1pf(zeta * zeta);
  const float a1 = 2.0f * zeta;

  int rowv[16];
  float dg[16];
#pragma unroll
  for (int r = 0; r < 16; ++r) {
    rowv[r] = 32 * R + (r & 3) + 8 * (r >> 2) + 4 * q;
    dg[r] = (rowv[r] == col) ? 1.0f : 0.0f;
  }

  // Stage Gis once; keep A- and B-role fragments in registers (loop-invariant).
  stageT(ws + GIS_OFF, Ah, Al, tid);
  __syncthreads();
  bf16x8 gAh[4], gAl[4], gBh[4], gBl[4];
#pragma unroll
  for (int kb = 0; kb < 4; ++kb) {
    gAh[kb] = readFrag(Ah, kb, q, 32 * R + ln);  // A-op Gis (stageT transpose)
    gAl[kb] = readFrag(Al, kb, q, 32 * R + ln);
    gBh[kb] = readFrag(Ah, kb, q, col);  // B-op Gis (symmetry)
    gBl[kb] = readFrag(Al, kb, q, col);
  }
  __syncthreads();

  float Mac[16];
#pragma unroll
  for (int r = 0; r < 16; ++r) Mac[r] = 0.0f;

  for (int it = 0; it < MATS_K3; ++it) {
    const int mat = blockIdx.x * MATS_K3 + it;
    stageT(x + (size_t)mat * MSIZE, Ah, Al, tid);
    __syncthreads();
    // mm1: P0 = X * Gis   (A = X frags from stageT, B = Gis regs)
    floatx16 acc;
#pragma unroll
    for (int r = 0; r < 16; ++r) acc[r] = 0.0f;
#pragma unroll
    for (int kb = 0; kb < 4; ++kb) {
      bf16x8 axh = readFrag(Ah, kb, q, 32 * R + ln);
      bf16x8 axl = readFrag(Al, kb, q, 32 * R + ln);
      acc = MFMA(axl, gBh[kb], acc);
      acc = MFMA(axh, gBl[kb], acc);
      acc = MFMA(axh, gBh[kb], acc);
    }
    float tmp[16];
#pragma unroll
    for (int r = 0; r < 16; ++r) tmp[r] = acc[r];
    storeChl(Bh, Bl, tmp, R, col, q);  // P0 direct (arr(k,n)=P0[k][n])
    __syncthreads();
    // mm2: S = Gis * P0 -> U = (S - mI)/h
#pragma unroll
    for (int r = 0; r < 16; ++r) acc[r] = 0.0f;
#pragma unroll
    for (int kb = 0; kb < 4; ++kb) {
      bf16x8 bph = readFrag(Bh, kb, q, col);
      bf16x8 bpl = readFrag(Bl, kb, q, col);
      acc = MFMA(gAl[kb], bph, acc);
      acc = MFMA(gAh[kb], bpl, acc);
      acc = MFMA(gAh[kb], bph, acc);
    }
    float u[16], tm1[16], tm2[16];
#pragma unroll
    for (int r = 0; r < 16; ++r) {
      u[r] = (acc[r] - m * dg[r]) * invh;
      Mac[r] += a0 * dg[r] + a1 * u[r];
      tm1[r] = u[r];
      tm2[r] = dg[r];
    }
    storeChl(Ah, Al, u, R, col, q);  // U direct (X dead)
    __syncthreads();
    bf16x8 uh[4], ul[4];
#pragma unroll
    for (int kb = 0; kb < 4; ++kb) {  // A-op U via symmetry
      uh[kb] = readFrag(Ah, kb, q, 32 * R + ln);
      ul[kb] = readFrag(Al, kb, q, 32 * R + ln);
    }
    // k = 2: T2 = 2 U*U - I (B-op U from LDS, hi/lo)
#pragma unroll
    for (int r = 0; r < 16; ++r) acc[r] = 0.0f;
#pragma unroll
    for (int kb = 0; kb < 4; ++kb) {
      bf16x8 buh = readFrag(Ah, kb, q, col);
      bf16x8 bul = readFrag(Al, kb, q, col);
      acc = MFMA(ul[kb], buh, acc);
      acc = MFMA(uh[kb], bul, acc);
      acc = MFMA(uh[kb], buh, acc);
    }
    float zk = zeta * zeta;
    float ak = -zk;  // -2*zk/2
    float t[16];
#pragma unroll
    for (int r = 0; r < 16; ++r) {
      t[r] = 2.0f * acc[r] - dg[r];
      Mac[r] += ak * t[r];
      tm2[r] = tm1[r];
      tm1[r] = t[r];
    }
    storeChi(Bh, t, R, col, q);  // T2 (bf16-only)
    __syncthreads();
    // k = 3..DEG: T_{k} = 2 U T_{k-1} - T_{k-2}; B-op bf16-only
    for (int k = 3; k <= DEG; ++k) {
      short* src = (k & 1) ? Bh : Ah;
      short* dst = (k & 1) ? Ah : Bh;
#pragma unroll
      for (int r = 0; r < 16; ++r) acc[r] = 0.0f;
#pragma unroll
      for (int kb = 0; kb < 4; ++kb) {
        bf16x8 b = readFrag(src, kb, q, col);
        acc = MFMA(ul[kb], b, acc);
        acc = MFMA(uh[kb], b, acc);
      }
      zk *= -zeta;
      ak = -2.0f * zk / (float)k;
#pragma unroll
      for (int r = 0; r < 16; ++r) {
        t[r] = 2.0f * acc[r] - tm2[r];
        Mac[r] += ak * t[r];
        tm2[r] = tm1[r];
        tm1[r] = t[r];
      }
      if (k < DEG) storeChi(dst, t, R, col, q);
      __syncthreads();
    }
  }
  float* dst = pm + (size_t)blockIdx.x * MSIZE;
#pragma unroll
  for (int r = 0; r < 16; ++r) dst[rowv[r] * 64 + col] = Mac[r];
}

// K4: E = expm(Mbar); G1 = Gs E Gs; Gis1 = sym(G1)^{-1/2}; C = Bs Gis1 -> ws.
__global__ __launch_bounds__(256) void k4_center(float* __restrict__ ws) {
  __shared__ __align__(16) float lA[MSIZE], lY[MSIZE], lZ[MSIZE], lW[MSIZE];
  __shared__ float red[257];
  const int tid = threadIdx.x;
  const int rt = tid >> 4, ct = tid & 15;
  loadMat(lA, ws + MBAR_OFF, tid);
  __syncthreads();
  if (tid == 0) {
    float mu = 0.f;
    for (int i = 0; i < NMAT; ++i) mu += lA[i * 65];
    red[256] = mu * (1.0f / NMAT);
  }
  __syncthreads();
  const float mu = red[256];
  float ss = 0.f;
#pragma unroll
  for (int j = 0; j < 4; ++j) {
    int base = j * 1024 + tid * 4;
    float4 v = *reinterpret_cast<const float4*>(lA + base);
    float4 idm = id4(base);
    v.x -= mu * idm.x;
    v.y -= mu * idm.y;
    v.z -= mu * idm.z;
    v.w -= mu * idm.w;
    ss += v.x * v.x + v.y * v.y + v.z * v.z + v.w * v.w;
    *reinterpret_cast<float4*>(lA + base) = v;
  }
  red[tid] = ss;
  __syncthreads();
  for (int off = 128; off > 0; off >>= 1) {
    if (tid < off) red[tid] += red[tid + off];
    __syncthreads();
  }
  float nrm = sqrtf(red[0]);
  int s = 0;
  while (nrm > 0.25f && s < 12) {
    nrm *= 0.5f;
    s++;
  }
  const float dscale = exp2f((float)-s);
#pragma unroll
  for (int j = 0; j < 4; ++j) {
    int base = j * 1024 + tid * 4;
    float4 v = *reinterpret_cast<const float4*>(lA + base);
    v.x *= dscale;
    v.y *= dscale;
    v.z *= dscale;
    v.w *= dscale;
    *reinterpret_cast<float4*>(lA + base) = v;
    float4 idm = id4(base);
    *reinterpret_cast<float4*>(lY + base) =
        make_float4(idm.x + v.x * 0.125f, idm.y + v.y * 0.125f,
                    idm.z + v.z * 0.125f, idm.w + v.w * 0.125f);
  }
  __syncthreads();
  float p[4][4];
  for (int j = 7; j >= 1; --j) {
    mm64T(lA, lY, rt, ct, p);
    __syncthreads();
    float w[4][4];
    const float rj = 1.0f / (float)j;
#pragma unroll
    for (int i = 0; i < 4; ++i)
#pragma unroll
      for (int jj = 0; jj < 4; ++jj)
        w[i][jj] =
            p[i][jj] * rj + (((rt * 4 + i) == (ct * 4 + jj)) ? 1.0f : 0.0f);
    storeTile(lY, rt, ct, w);
    __syncthreads();
  }
  for (int tq = 0; tq < s; ++tq) {
    mm64T(lY, lY, rt, ct, p);
    __syncthreads();
    storeTile(lY, rt, ct, p);
    __syncthreads();
  }
  const float emu = expf(mu);
#pragma unroll
  for (int j = 0; j < 4; ++j) {
    int base = j * 1024 + tid * 4;
    float4 v = *reinterpret_cast<const float4*>(lY + base);
    v.x *= emu;
    v.y *= emu;
    v.z *= emu;
    v.w *= emu;
    *reinterpret_cast<float4*>(lY + base) = v;
  }
  __syncthreads();
  loadMat(lZ, ws + GS_OFF, tid);
  __syncthreads();
  mm64T(lY, lZ, rt, ct, p);  // E Gs
  __syncthreads();
  storeTile(lW, rt, ct, p);
  __syncthreads();
  mm64T(lZ, lW, rt, ct, p);  // G1 = Gs E Gs
  __syncthreads();
  storeTile(lA, rt, ct, p);
  __syncthreads();
  float qq[4][4];
#pragma unroll
  for (int i = 0; i < 4; ++i)
#pragma unroll
    for (int j = 0; j < 4; ++j)
      qq[i][j] = 0.5f * (p[i][j] + lA[(ct * 4 + j) * NMAT + rt * 4 + i]);
  __syncthreads();
  storeTile(lA, rt, ct, qq);
  __syncthreads();
  float c = block_ns(lA, lY, lZ, lW, red, NS_ITERS_MEAN);
  const float rs = 1.0f / sqrtf(c);
#pragma unroll
  for (int j = 0; j < 4; ++j) {  // Gis1 -> lY
    int base = j * 1024 + tid * 4;
    float4 v = *reinterpret_cast<const float4*>(lZ + base);
    *reinterpret_cast<float4*>(lY + base) =
        make_float4(v.x * rs, v.y * rs, v.z * rs, v.w * rs);
  }
  __syncthreads();
  loadMat(lZ, ws + BS_OFF, tid);
  __syncthreads();
  mm64T(lZ, lY, rt, ct, p);  // C = Bs Gis1
#pragma unroll
  for (int i = 0; i < 4; ++i)
#pragma unroll
    for (int j = 0; j < 4; ++j)
      ws[C_OFF + (rt * 4 + i) * NMAT + ct * 4 + j] = p[i][j];
}

// ============================ K5: out = C X C^T (MFMA) ======================
// 256 threads, 8 mats/block, grid 1024 (4 blocks/CU).
// mm1: P' = X*C^T (A = X frags, B = C^T frags); mm2: O = C*P'.
__global__ __launch_bounds__(256) void k5_out_mfma(const float* __restrict__ x,
                                                   const float* __restrict__ ws,
                                                   float* __restrict__ out) {
  __shared__ __align__(16) short SH[4][GSTR * 8];
  const int tid = threadIdx.x;
  const int w4 = tid >> 6;
  const int R = w4 >> 1, Cb = w4 & 1;
  const int lane = tid & 63;
  const int ln = lane & 31, q = lane >> 5;
  const int col = 32 * Cb + ln;
  short* Ah = SH[0];
  short* Al = SH[1];
  short* Bh = SH[2];
  short* Bl = SH[3];

  int rowv[16];
#pragma unroll
  for (int r = 0; r < 16; ++r)
    rowv[r] = 32 * R + (r & 3) + 8 * (r >> 2) + 4 * q;

  stageT(ws + C_OFF, Ah, Al, tid);  // arr(k,n) = C[n][k] = C^T(k,n)
  __syncthreads();
  bf16x8 cAh[4], cAl[4], ctBh[4], ctBl[4];
#pragma unroll
  for (int kb = 0; kb < 4; ++kb) {
    cAh[kb] = readFrag(Ah, kb, q, 32 * R + ln);  // A-op C
    cAl[kb] = readFrag(Al, kb, q, 32 * R + ln);
    ctBh[kb] = readFrag(Ah, kb, q, col);  // B-op C^T
    ctBl[kb] = readFrag(Al, kb, q, col);
  }
  __syncthreads();

  for (int it = 0; it < MATS_K5; ++it) {
    const int mat = blockIdx.x * MATS_K5 + it;
    stageT(x + (size_t)mat * MSIZE, Ah, Al, tid);
    __syncthreads();
    floatx16 acc;
#pragma unroll
    for (int r = 0; r < 16; ++r) acc[r] = 0.0f;
#pragma unroll
    for (int kb = 0; kb < 4; ++kb) {
      bf16x8 axh = readFrag(Ah, kb, q, 32 * R + ln);
      bf16x8 axl = readFrag(Al, kb, q, 32 * R + ln);
      acc = MFMA(axl, ctBh[kb], acc);
      acc = MFMA(axh, ctBl[kb], acc);
      acc = MFMA(axh, ctBh[kb], acc);
    }
    float tmp[16];
#pragma unroll
    for (int r = 0; r < 16; ++r) tmp[r] = acc[r];
    storeChl(Bh, Bl, tmp, R, col, q);  // P' direct
    __syncthreads();
#pragma unroll
    for (int r = 0; r < 16; ++r) acc[r] = 0.0f;
#pragma unroll
    for (int kb = 0; kb < 4; ++kb) {
      bf16x8 bph = readFrag(Bh, kb, q, col);
      bf16x8 bpl = readFrag(Bl, kb, q, col);
      acc = MFMA(cAl[kb], bph, acc);
      acc = MFMA(cAh[kb], bpl, acc);
      acc = MFMA(cAh[kb], bph, acc);
    }
    float* dst = out + (size_t)mat * MSIZE;
#pragma unroll
    for (int r = 0; r < 16; ++r) dst[rowv[r] * 64 + col] = acc[r];
    __syncthreads();
  }
}

extern "C" void kernel_launch(void* const* d_in, const int* in_sizes, int n_in,
                              void* d_out, int out_size, void* d_ws,
                              size_t ws_size, hipStream_t stream) {
  const float* x = (const float*)d_in[0];
  const float* bias = (const float*)d_in[1];
  float* out = (float*)d_out;
  float* ws = (float*)d_ws;
  const float invB = 1.0f / (float)BATCH;
  float* red1 = out + (size_t)RED1_SLOT * MSIZE;  // 16 stage-1 slots in out

  k1_mean_bias<<<NBLK_RED + 1, 256, 0, stream>>>(x, bias, ws, out);
  k_reduce_parts<<<dim3(4, 16), 256, 0, stream>>>(out, red1, NBLK_RED, 1.0f);
  k_reduce_parts<<<dim3(4, 1), 256, 0, stream>>>(red1, ws + G_OFF, 16, invB);
  k2_mean_ns<<<1, 256, 0, stream>>>(ws);
  k3_logsum_mfma<<<NBLK_K3, 256, 0, stream>>>(x, ws, out);
  k_reduce_parts<<<dim3(4, 16), 256, 0, stream>>>(out, red1, NBLK_K3, 1.0f);
  k_reduce_parts<<<dim3(4, 1), 256, 0, stream>>>(red1, ws + MBAR_OFF, 16, invB);
  k4_center<<<1, 256, 0, stream>>>(ws);
  k5_out_mfma<<<NBLK_K5, 256, 0, stream>>>(x, ws, out);
}

// Round 4
// 790.582 us; speedup vs baseline: 1.0066x; 1.0066x over previous
//
#include <hip/hip_runtime.h>

// ---------------------------------------------------------------------------
// SPDBatchNormMean forward, B=8192, n=64, fp32. Eigendecomp-free:
//   G0 = mean(x); Gs/Gis = G0^{±1/2} (Newton-Schulz); M = mean log(Gis x Gis)
//   (deg-18 Chebyshev on [0.3,4.0]); G1 = Gs expm(M) Gs; Gis1 = G1^{-1/2};
//   C = Bs Gis1 (Bs = bias^{1/2}); out = C x C^T.
// Round 6: risk-reduced in-block-occupancy variant. The 146KB-LDS version
// failed the container twice; the only unproven parameter was LDS > 128KB.
// This version keeps 1024-thread blocks (16 waves, 4 independent 4-wave
// chains, grid 256 = 1 block/CU) but drops per-chain LDS from 4 arrays to 3
// (k3) / 2 (k5) by overlapping buffers with +2 barriers per matrix:
//   X staged in (A0,A1) -> mm1 -> barrier -> P0 overwrites (A0,A1) ->
//   barrier -> mm2 -> U overwrites (A0,A1) -> T2 into A2 -> recurrence
//   ping-pongs A2 <-> A0 (U lives in registers uh/ul).
// k3 LDS: 4*3*8320 + Gis pair 16640 = 116,480 B (113.7 KB, < proven 128KB).
// k5 LDS: 4*2*8320 + C pair = 83,200 B.
// ---------------------------------------------------------------------------

#define BATCH 8192
#define NMAT 64
#define MSIZE 4096
#define NBLK_RED 512
#define NBLK_K3 256
#define K3_CHAINS 4
#define CHAIN_MATS 8
#define NBLK_K5 256
#define DEG 18
#define CHEB_LO 0.30f
#define CHEB_HI 4.00f
#define NS_ITERS_MEAN 10
#define NS_ITERS_BIAS 12
#define GSTR 520 /* padded k-group stride (65*8 elems, 16B-aligned) */

// workspace layout (floats): only the 6 small matrices (96 KB).
#define G_OFF 0
#define BS_OFF (G_OFF + MSIZE)
#define GS_OFF (BS_OFF + MSIZE)
#define GIS_OFF (GS_OFF + MSIZE)
#define MBAR_OFF (GIS_OFF + MSIZE)
#define C_OFF (MBAR_OFF + MSIZE)
// scratch staged in `out` (128 MB, dead until k5): partial slots [0,1024),
// stage-1 reduce slots at [RED1_SLOT, RED1_SLOT+64).
#define RED1_SLOT 2048

typedef __attribute__((ext_vector_type(8))) short bf16x8;
typedef __attribute__((ext_vector_type(16))) float floatx16;
#define MFMA(a, b, c) __builtin_amdgcn_mfma_f32_32x32x16_bf16(a, b, c, 0, 0, 0)

__device__ __forceinline__ short f2bf(float x) {
  union {
    __bf16 b;
    short s;
  } u;
  u.b = (__bf16)x;  // hardware cvt, RNE
  return u.s;
}
__device__ __forceinline__ float bf2f(short h) {
  return __uint_as_float(((unsigned)(unsigned short)h) << 16);
}

// Stage a row-major 64x64 fp32 global matrix M into hi/lo bf16 LDS arrays in
// B-layout holding M^T: arr(k,n) = M[n][k]. 256 threads (st), packed b64.
__device__ __forceinline__ void stageT(const float* __restrict__ src, short* ah,
                                       short* al, int st) {
#pragma unroll
  for (int jb = 0; jb < 4; ++jb) {
    int flat = jb * 1024 + st * 4;
    float4 v = *reinterpret_cast<const float4*>(src + flat);
    int i = flat >> 6;   // row of M
    int j0 = flat & 63;  // col base (multiple of 4)
    int addr = (j0 >> 3) * GSTR + i * 8 + (j0 & 7);
    short4 h, l;
    h.x = f2bf(v.x); l.x = f2bf(v.x - bf2f(h.x));
    h.y = f2bf(v.y); l.y = f2bf(v.y - bf2f(h.y));
    h.z = f2bf(v.z); l.z = f2bf(v.z - bf2f(h.z));
    h.w = f2bf(v.w); l.w = f2bf(v.w - bf2f(h.w));
    *reinterpret_cast<short4*>(ah + addr) = h;
    *reinterpret_cast<short4*>(al + addr) = l;
  }
}

// Fragment read: returns elements j=0..7 at k = kb*16 + q*8 + j, column n.
__device__ __forceinline__ bf16x8 readFrag(const short* a, int kb, int q,
                                           int n) {
  return *reinterpret_cast<const bf16x8*>(a + (kb * 2 + q) * GSTR + n * 8);
}

// Store 16 C/D-layout fp32 regs into B-layout array(s) as bf16 (direct:
// arr(k=row, n=col) = v). Packs 4 consecutive rows per b64 write.
__device__ __forceinline__ void storeChi(short* dh, const float* v, int R,
                                         int col, int q) {
#pragma unroll
  for (int g4 = 0; g4 < 4; ++g4) {
    int addr = (4 * R + g4) * GSTR + col * 8 + 4 * q;
    short4 h;
    h.x = f2bf(v[4 * g4 + 0]);
    h.y = f2bf(v[4 * g4 + 1]);
    h.z = f2bf(v[4 * g4 + 2]);
    h.w = f2bf(v[4 * g4 + 3]);
    *reinterpret_cast<short4*>(dh + addr) = h;
  }
}
__device__ __forceinline__ void storeChl(short* dh, short* dl, const float* v,
                                         int R, int col, int q) {
#pragma unroll
  for (int g4 = 0; g4 < 4; ++g4) {
    int addr = (4 * R + g4) * GSTR + col * 8 + 4 * q;
    short4 h, l;
    float a0 = v[4 * g4 + 0], a1 = v[4 * g4 + 1];
    float a2 = v[4 * g4 + 2], a3 = v[4 * g4 + 3];
    h.x = f2bf(a0); l.x = f2bf(a0 - bf2f(h.x));
    h.y = f2bf(a1); l.y = f2bf(a1 - bf2f(h.y));
    h.z = f2bf(a2); l.z = f2bf(a2 - bf2f(h.z));
    h.w = f2bf(a3); l.w = f2bf(a3 - bf2f(h.w));
    *reinterpret_cast<short4*>(dh + addr) = h;
    *reinterpret_cast<short4*>(dl + addr) = l;
  }
}

// ============================ vector-ALU helpers (k1/k2/k4) ================

__device__ __forceinline__ void mm64T(const float* __restrict__ A,
                                      const float* __restrict__ B, int rt,
                                      int ct, float p[4][4]) {
#pragma unroll
  for (int i = 0; i < 4; ++i)
#pragma unroll
    for (int j = 0; j < 4; ++j) p[i][j] = 0.0f;
#pragma unroll 4
  for (int k = 0; k < NMAT; ++k) {
    float4 a = *reinterpret_cast<const float4*>(A + k * NMAT + rt * 4);
    float4 b = *reinterpret_cast<const float4*>(B + k * NMAT + ct * 4);
    p[0][0] = fmaf(a.x, b.x, p[0][0]);
    p[0][1] = fmaf(a.x, b.y, p[0][1]);
    p[0][2] = fmaf(a.x, b.z, p[0][2]);
    p[0][3] = fmaf(a.x, b.w, p[0][3]);
    p[1][0] = fmaf(a.y, b.x, p[1][0]);
    p[1][1] = fmaf(a.y, b.y, p[1][1]);
    p[1][2] = fmaf(a.y, b.z, p[1][2]);
    p[1][3] = fmaf(a.y, b.w, p[1][3]);
    p[2][0] = fmaf(a.z, b.x, p[2][0]);
    p[2][1] = fmaf(a.z, b.y, p[2][1]);
    p[2][2] = fmaf(a.z, b.z, p[2][2]);
    p[2][3] = fmaf(a.z, b.w, p[2][3]);
    p[3][0] = fmaf(a.w, b.x, p[3][0]);
    p[3][1] = fmaf(a.w, b.y, p[3][1]);
    p[3][2] = fmaf(a.w, b.z, p[3][2]);
    p[3][3] = fmaf(a.w, b.w, p[3][3]);
  }
}

__device__ __forceinline__ void storeTile(float* dst, int rt, int ct,
                                          const float p[4][4]) {
#pragma unroll
  for (int i = 0; i < 4; ++i)
    *reinterpret_cast<float4*>(dst + (rt * 4 + i) * NMAT + ct * 4) =
        make_float4(p[i][0], p[i][1], p[i][2], p[i][3]);
}

__device__ __forceinline__ void loadMat(float* dst,
                                        const float* __restrict__ src,
                                        int tid) {
#pragma unroll
  for (int j = 0; j < 4; ++j)
    *reinterpret_cast<float4*>(dst + j * 1024 + tid * 4) =
        *reinterpret_cast<const float4*>(src + j * 1024 + tid * 4);
}

__device__ __forceinline__ float4 id4(int base) {
  return make_float4(((base + 0) % 65) == 0 ? 1.f : 0.f,
                     ((base + 1) % 65) == 0 ? 1.f : 0.f,
                     ((base + 2) % 65) == 0 ? 1.f : 0.f,
                     ((base + 3) % 65) == 0 ? 1.f : 0.f);
}

__device__ float block_ns(const float* lA, float* lY, float* lZ, float* lW,
                          float* red, int iters) {
  const int tid = threadIdx.x;
  const int rt = tid >> 4, ct = tid & 15;
  float ss = 0.0f;
#pragma unroll
  for (int j = 0; j < 4; ++j) {
    float4 v = *reinterpret_cast<const float4*>(lA + j * 1024 + tid * 4);
    ss += v.x * v.x + v.y * v.y + v.z * v.z + v.w * v.w;
  }
  red[tid] = ss;
  __syncthreads();
  for (int off = 128; off > 0; off >>= 1) {
    if (tid < off) red[tid] += red[tid + off];
    __syncthreads();
  }
  const float c = sqrtf(red[0] * 0.5f);
  const float rc = 1.0f / c;
#pragma unroll
  for (int j = 0; j < 4; ++j) {
    int base = j * 1024 + tid * 4;
    float4 v = *reinterpret_cast<const float4*>(lA + base);
    v.x *= rc;
    v.y *= rc;
    v.z *= rc;
    v.w *= rc;
    *reinterpret_cast<float4*>(lY + base) = v;
    *reinterpret_cast<float4*>(lZ + base) = id4(base);
  }
  __syncthreads();
  for (int it = 0; it < iters; ++it) {
    float p[4][4];
    mm64T(lZ, lY, rt, ct, p);
    float w[4][4];
#pragma unroll
    for (int i = 0; i < 4; ++i)
#pragma unroll
      for (int j = 0; j < 4; ++j)
        w[i][j] = ((rt * 4 + i) == (ct * 4 + j) ? 1.5f : 0.0f) - 0.5f * p[i][j];
    storeTile(lW, rt, ct, w);
    __syncthreads();
    float py[4][4], pz[4][4];
    mm64T(lY, lW, rt, ct, py);
    mm64T(lW, lZ, rt, ct, pz);
    __syncthreads();
    storeTile(lY, rt, ct, py);
    storeTile(lZ, rt, ct, pz);
    __syncthreads();
  }
  return c;
}

// K1: blocks [0,NBLK_RED) partial-sum x into `pg` (out scratch); block
// NBLK_RED does Bs = bias^{1/2}.
__global__ __launch_bounds__(256) void k1_mean_bias(
    const float* __restrict__ x, const float* __restrict__ bias,
    float* __restrict__ ws, float* __restrict__ pg) {
  const int tid = threadIdx.x;
  if (blockIdx.x < NBLK_RED) {
    float acc[16];
#pragma unroll
    for (int j = 0; j < 16; ++j) acc[j] = 0.f;
    for (int i = blockIdx.x; i < BATCH; i += NBLK_RED) {
      const float* src = x + (size_t)i * MSIZE;
#pragma unroll
      for (int j = 0; j < 4; ++j) {
        float4 v = *reinterpret_cast<const float4*>(src + j * 1024 + tid * 4);
        acc[j * 4 + 0] += v.x;
        acc[j * 4 + 1] += v.y;
        acc[j * 4 + 2] += v.z;
        acc[j * 4 + 3] += v.w;
      }
    }
    float* dst = pg + (size_t)blockIdx.x * MSIZE;
#pragma unroll
    for (int j = 0; j < 4; ++j)
      *reinterpret_cast<float4*>(dst + j * 1024 + tid * 4) = make_float4(
          acc[j * 4 + 0], acc[j * 4 + 1], acc[j * 4 + 2], acc[j * 4 + 3]);
  } else {
    __shared__ __align__(16) float lA[MSIZE], lY[MSIZE], lZ[MSIZE], lW[MSIZE];
    __shared__ float red[257];
    loadMat(lA, bias, tid);
    __syncthreads();
    float c = block_ns(lA, lY, lZ, lW, red, NS_ITERS_BIAS);
    float sc = sqrtf(c);
#pragma unroll
    for (int j = 0; j < 4; ++j) {
      int base = j * 1024 + tid * 4;
      float4 v = *reinterpret_cast<const float4*>(lY + base);
      v.x *= sc;
      v.y *= sc;
      v.z *= sc;
      v.w *= sc;
      *reinterpret_cast<float4*>(ws + BS_OFF + base) = v;
    }
  }
}

// Two-stage partial reduce. grid = (4, NY): block (bx, by) sums parts
// p = by, by+NY, ... for its 1 KB element range; writes slot `by` of dst.
__global__ __launch_bounds__(256) void k_reduce_parts(
    const float* __restrict__ src, float* __restrict__ dst, int nparts,
    float scale) {
  int e4 = blockIdx.x * 256 + threadIdx.x;
  float4 acc = make_float4(0.f, 0.f, 0.f, 0.f);
  for (int b = blockIdx.y; b < nparts; b += gridDim.y) {
    float4 v =
        *reinterpret_cast<const float4*>(src + (size_t)b * MSIZE + e4 * 4);
    acc.x += v.x;
    acc.y += v.y;
    acc.z += v.z;
    acc.w += v.w;
  }
  acc.x *= scale;
  acc.y *= scale;
  acc.z *= scale;
  acc.w *= scale;
  *reinterpret_cast<float4*>(dst + (size_t)blockIdx.y * MSIZE + e4 * 4) = acc;
}

__global__ __launch_bounds__(256) void k2_mean_ns(float* __restrict__ ws) {
  __shared__ __align__(16) float lA[MSIZE], lY[MSIZE], lZ[MSIZE], lW[MSIZE];
  __shared__ float red[257];
  const int tid = threadIdx.x;
  loadMat(lA, ws + G_OFF, tid);
  __syncthreads();
  float c = block_ns(lA, lY, lZ, lW, red, NS_ITERS_MEAN);
  float sc = sqrtf(c), rs = 1.0f / sqrtf(c);
#pragma unroll
  for (int j = 0; j < 4; ++j) {
    int base = j * 1024 + tid * 4;
    float4 y = *reinterpret_cast<const float4*>(lY + base);
    float4 z = *reinterpret_cast<const float4*>(lZ + base);
    *reinterpret_cast<float4*>(ws + GS_OFF + base) =
        make_float4(y.x * sc, y.y * sc, y.z * sc, y.w * sc);
    *reinterpret_cast<float4*>(ws + GIS_OFF + base) =
        make_float4(z.x * rs, z.y * rs, z.z * rs, z.w * rs);
  }
}

// ============================ K3: MFMA Chebyshev log-sum ====================
// 1024 threads = 4 independent 4-wave chains; grid 256 (1 block/CU, 16 waves).
// 3 LDS arrays per chain (A0,A1,A2): X/P0/U time-share (A0,A1) with extra
// barriers; recurrence ping-pongs A2 <-> A0 (U cached in registers).
__global__ __launch_bounds__(1024) void k3_logsum_mfma(
    const float* __restrict__ x, const float* __restrict__ ws,
    float* __restrict__ pm) {
  __shared__ __align__(16) short GisH[GSTR * 8], GisL[GSTR * 8];
  __shared__ __align__(16) short SH[K3_CHAINS][3][GSTR * 8];
  const int tid = threadIdx.x;
  const int ch = tid >> 8;   // chain 0..3
  const int ct = tid & 255;  // thread within chain
  const int w4 = ct >> 6;    // wave within chain
  const int R = w4 >> 1, Cb = w4 & 1;
  const int lane = tid & 63;
  const int ln = lane & 31, q = lane >> 5;
  const int col = 32 * Cb + ln;
  short* A0 = SH[ch][0];
  short* A1 = SH[ch][1];
  short* A2 = SH[ch][2];

  const float m = 0.5f * (CHEB_LO + CHEB_HI), hh = 0.5f * (CHEB_HI - CHEB_LO);
  const float invh = 1.0f / hh;
  const float beta = hh / m;
  const float zeta = (1.0f - sqrtf(1.0f - beta * beta)) / beta;
  const float ca0 = logf(m) - log1pf(zeta * zeta);
  const float ca1 = 2.0f * zeta;

  // diagonal index: r_dg = r for which row(r)==col (or -1). row(r) =
  // 32R + (r&3) + 8(r>>2) + 4q.
  int d = col - 32 * R - 4 * q;
  const int r_dg =
      (d >= 0 && d < 32 && (d & 4) == 0) ? ((d >> 3) * 4 + (d & 3)) : -1;

  if (ch == 0) stageT(ws + GIS_OFF, GisH, GisL, ct);
  __syncthreads();

  float Mac[16];
#pragma unroll
  for (int r = 0; r < 16; ++r) Mac[r] = 0.0f;

  for (int it = 0; it < CHAIN_MATS; ++it) {
    const int mat = blockIdx.x * (K3_CHAINS * CHAIN_MATS) + ch * CHAIN_MATS + it;
    stageT(x + (size_t)mat * MSIZE, A0, A1, ct);
    __syncthreads();
    // mm1: P0 = X * Gis   (A = X frags from A0/A1, B = Gis shared)
    floatx16 acc;
#pragma unroll
    for (int r = 0; r < 16; ++r) acc[r] = 0.0f;
#pragma unroll
    for (int kb = 0; kb < 4; ++kb) {
      bf16x8 axh = readFrag(A0, kb, q, 32 * R + ln);
      bf16x8 axl = readFrag(A1, kb, q, 32 * R + ln);
      bf16x8 gbh = readFrag(GisH, kb, q, col);
      bf16x8 gbl = readFrag(GisL, kb, q, col);
      acc = MFMA(axl, gbh, acc);
      acc = MFMA(axh, gbl, acc);
      acc = MFMA(axh, gbh, acc);
    }
    __syncthreads();  // all waves finished reading X from A0/A1
    float tmp[16];
#pragma unroll
    for (int r = 0; r < 16; ++r) tmp[r] = acc[r];
    storeChl(A0, A1, tmp, R, col, q);  // P0 overwrites X
    __syncthreads();
    // mm2: S = Gis * P0 -> U = (S - mI)/h
#pragma unroll
    for (int r = 0; r < 16; ++r) acc[r] = 0.0f;
#pragma unroll
    for (int kb = 0; kb < 4; ++kb) {
      bf16x8 gah = readFrag(GisH, kb, q, 32 * R + ln);
      bf16x8 gal = readFrag(GisL, kb, q, 32 * R + ln);
      bf16x8 bph = readFrag(A0, kb, q, col);
      bf16x8 bpl = readFrag(A1, kb, q, col);
      acc = MFMA(gal, bph, acc);
      acc = MFMA(gah, bpl, acc);
      acc = MFMA(gah, bph, acc);
    }
    float u[16], tm1[16], tm2[16];
#pragma unroll
    for (int r = 0; r < 16; ++r) {
      float dgr = (r == r_dg) ? 1.0f : 0.0f;
      u[r] = (acc[r] - m * dgr) * invh;
      Mac[r] += ca0 * dgr + ca1 * u[r];
      tm1[r] = u[r];
      tm2[r] = dgr;  // T0 = I
    }
    __syncthreads();  // all waves finished reading P0 from A0/A1
    storeChl(A0, A1, u, R, col, q);  // U overwrites P0
    __syncthreads();
    bf16x8 uh[4], ul[4];
#pragma unroll
    for (int kb = 0; kb < 4; ++kb) {  // A-op U via symmetry -> registers
      uh[kb] = readFrag(A0, kb, q, 32 * R + ln);
      ul[kb] = readFrag(A1, kb, q, 32 * R + ln);
    }
    // k = 2: T2 = 2 U*U - I (B-op U from A0/A1, hi/lo)
#pragma unroll
    for (int r = 0; r < 16; ++r) acc[r] = 0.0f;
#pragma unroll
    for (int kb = 0; kb < 4; ++kb) {
      bf16x8 buh = readFrag(A0, kb, q, col);
      bf16x8 bul = readFrag(A1, kb, q, col);
      acc = MFMA(ul[kb], buh, acc);
      acc = MFMA(uh[kb], bul, acc);
      acc = MFMA(uh[kb], buh, acc);
    }
    float zk = zeta * zeta;
    float ak = -zk;  // -2*zk/2
    float t[16];
#pragma unroll
    for (int r = 0; r < 16; ++r) {
      t[r] = 2.0f * acc[r] - tm2[r];  // tm2 == T0 here
      Mac[r] += ak * t[r];
      tm2[r] = tm1[r];
      tm1[r] = t[r];
    }
    storeChi(A2, t, R, col, q);  // T2 -> A2 (A2 idle; no WAR with A0/A1 reads)
    __syncthreads();
    // k = 3..DEG: T_k = 2 U T_{k-1} - T_{k-2}; B-op bf16-only; ping-pong
    // A2 (even T) <-> A0 (odd T). U stays in registers; A0's U copy is dead.
    for (int k = 3; k <= DEG; ++k) {
      short* src = (k & 1) ? A2 : A0;
      short* dst = (k & 1) ? A0 : A2;
#pragma unroll
      for (int r = 0; r < 16; ++r) acc[r] = 0.0f;
#pragma unroll
      for (int kb = 0; kb < 4; ++kb) {
        bf16x8 b = readFrag(src, kb, q, col);
        acc = MFMA(ul[kb], b, acc);
        acc = MFMA(uh[kb], b, acc);
      }
      zk *= -zeta;
      ak = -2.0f * zk / (float)k;
#pragma unroll
      for (int r = 0; r < 16; ++r) {
        t[r] = 2.0f * acc[r] - tm2[r];
        Mac[r] += ak * t[r];
        tm2[r] = tm1[r];
        tm1[r] = t[r];
      }
      if (k < DEG) storeChi(dst, t, R, col, q);
      __syncthreads();
    }
  }
  // per-chain partial (1024 total)
  float* dst = pm + (size_t)(blockIdx.x * K3_CHAINS + ch) * MSIZE;
#pragma unroll
  for (int r = 0; r < 16; ++r) {
    int row = 32 * R + (r & 3) + 8 * (r >> 2) + 4 * q;
    dst[row * 64 + col] = Mac[r];
  }
}

// K4: E = expm(Mbar); G1 = Gs E Gs; Gis1 = sym(G1)^{-1/2}; C = Bs Gis1 -> ws.
__global__ __launch_bounds__(256) void k4_center(float* __restrict__ ws) {
  __shared__ __align__(16) float lA[MSIZE], lY[MSIZE], lZ[MSIZE], lW[MSIZE];
  __shared__ float red[257];
  const int tid = threadIdx.x;
  const int rt = tid >> 4, ct = tid & 15;
  loadMat(lA, ws + MBAR_OFF, tid);
  __syncthreads();
  if (tid == 0) {
    float mu = 0.f;
    for (int i = 0; i < NMAT; ++i) mu += lA[i * 65];
    red[256] = mu * (1.0f / NMAT);
  }
  __syncthreads();
  const float mu = red[256];
  float ss = 0.f;
#pragma unroll
  for (int j = 0; j < 4; ++j) {
    int base = j * 1024 + tid * 4;
    float4 v = *reinterpret_cast<const float4*>(lA + base);
    float4 idm = id4(base);
    v.x -= mu * idm.x;
    v.y -= mu * idm.y;
    v.z -= mu * idm.z;
    v.w -= mu * idm.w;
    ss += v.x * v.x + v.y * v.y + v.z * v.z + v.w * v.w;
    *reinterpret_cast<float4*>(lA + base) = v;
  }
  red[tid] = ss;
  __syncthreads();
  for (int off = 128; off > 0; off >>= 1) {
    if (tid < off) red[tid] += red[tid + off];
    __syncthreads();
  }
  float nrm = sqrtf(red[0]);
  int s = 0;
  while (nrm > 0.25f && s < 12) {
    nrm *= 0.5f;
    s++;
  }
  const float dscale = exp2f((float)-s);
#pragma unroll
  for (int j = 0; j < 4; ++j) {
    int base = j * 1024 + tid * 4;
    float4 v = *reinterpret_cast<const float4*>(lA + base);
    v.x *= dscale;
    v.y *= dscale;
    v.z *= dscale;
    v.w *= dscale;
    *reinterpret_cast<float4*>(lA + base) = v;
    float4 idm = id4(base);
    *reinterpret_cast<float4*>(lY + base) =
        make_float4(idm.x + v.x * 0.125f, idm.y + v.y * 0.125f,
                    idm.z + v.z * 0.125f, idm.w + v.w * 0.125f);
  }
  __syncthreads();
  float p[4][4];
  for (int j = 7; j >= 1; --j) {
    mm64T(lA, lY, rt, ct, p);
    __syncthreads();
    float w[4][4];
    const float rj = 1.0f / (float)j;
#pragma unroll
    for (int i = 0; i < 4; ++i)
#pragma unroll
      for (int jj = 0; jj < 4; ++jj)
        w[i][jj] =
            p[i][jj] * rj + (((rt * 4 + i) == (ct * 4 + jj)) ? 1.0f : 0.0f);
    storeTile(lY, rt, ct, w);
    __syncthreads();
  }
  for (int tq = 0; tq < s; ++tq) {
    mm64T(lY, lY, rt, ct, p);
    __syncthreads();
    storeTile(lY, rt, ct, p);
    __syncthreads();
  }
  const float emu = expf(mu);
#pragma unroll
  for (int j = 0; j < 4; ++j) {
    int base = j * 1024 + tid * 4;
    float4 v = *reinterpret_cast<const float4*>(lY + base);
    v.x *= emu;
    v.y *= emu;
    v.z *= emu;
    v.w *= emu;
    *reinterpret_cast<float4*>(lY + base) = v;
  }
  __syncthreads();
  loadMat(lZ, ws + GS_OFF, tid);
  __syncthreads();
  mm64T(lY, lZ, rt, ct, p);  // E Gs
  __syncthreads();
  storeTile(lW, rt, ct, p);
  __syncthreads();
  mm64T(lZ, lW, rt, ct, p);  // G1 = Gs E Gs
  __syncthreads();
  storeTile(lA, rt, ct, p);
  __syncthreads();
  float qq[4][4];
#pragma unroll
  for (int i = 0; i < 4; ++i)
#pragma unroll
    for (int j = 0; j < 4; ++j)
      qq[i][j] = 0.5f * (p[i][j] + lA[(ct * 4 + j) * NMAT + rt * 4 + i]);
  __syncthreads();
  storeTile(lA, rt, ct, qq);
  __syncthreads();
  float c = block_ns(lA, lY, lZ, lW, red, NS_ITERS_MEAN);
  const float rs = 1.0f / sqrtf(c);
#pragma unroll
  for (int j = 0; j < 4; ++j) {  // Gis1 -> lY
    int base = j * 1024 + tid * 4;
    float4 v = *reinterpret_cast<const float4*>(lZ + base);
    *reinterpret_cast<float4*>(lY + base) =
        make_float4(v.x * rs, v.y * rs, v.z * rs, v.w * rs);
  }
  __syncthreads();
  loadMat(lZ, ws + BS_OFF, tid);
  __syncthreads();
  mm64T(lZ, lY, rt, ct, p);  // C = Bs Gis1
#pragma unroll
  for (int i = 0; i < 4; ++i)
#pragma unroll
    for (int j = 0; j < 4; ++j)
      ws[C_OFF + (rt * 4 + i) * NMAT + ct * 4 + j] = p[i][j];
}

// ============================ K5: out = C X C^T (MFMA) ======================
// 1024 threads = 4 chains, grid 256 (1 block/CU, 16 waves). C^T staged once
// per block into a shared LDS pair. 2 LDS arrays per chain: X then P'
// time-share (A0,A1) with one extra barrier.
// mm1: P' = X*C^T (A = X frags, B = C^T frags); mm2: O = C*P'.
__global__ __launch_bounds__(1024) void k5_out_mfma(const float* __restrict__ x,
                                                    const float* __restrict__ ws,
                                                    float* __restrict__ out) {
  __shared__ __align__(16) short CtH[GSTR * 8], CtL[GSTR * 8];
  __shared__ __align__(16) short SH[K3_CHAINS][2][GSTR * 8];
  const int tid = threadIdx.x;
  const int ch = tid >> 8;
  const int ct = tid & 255;
  const int w4 = ct >> 6;
  const int R = w4 >> 1, Cb = w4 & 1;
  const int lane = tid & 63;
  const int ln = lane & 31, q = lane >> 5;
  const int col = 32 * Cb + ln;
  short* A0 = SH[ch][0];
  short* A1 = SH[ch][1];

  if (ch == 0) stageT(ws + C_OFF, CtH, CtL, ct);  // arr(k,n) = C[n][k]
  __syncthreads();

  for (int it = 0; it < CHAIN_MATS; ++it) {
    const int mat = blockIdx.x * (K3_CHAINS * CHAIN_MATS) + ch * CHAIN_MATS + it;
    stageT(x + (size_t)mat * MSIZE, A0, A1, ct);
    __syncthreads();
    floatx16 acc;
#pragma unroll
    for (int r = 0; r < 16; ++r) acc[r] = 0.0f;
#pragma unroll
    for (int kb = 0; kb < 4; ++kb) {
      bf16x8 axh = readFrag(A0, kb, q, 32 * R + ln);
      bf16x8 axl = readFrag(A1, kb, q, 32 * R + ln);
      bf16x8 cbh = readFrag(CtH, kb, q, col);  // B-op C^T
      bf16x8 cbl = readFrag(CtL, kb, q, col);
      acc = MFMA(axl, cbh, acc);
      acc = MFMA(axh, cbl, acc);
      acc = MFMA(axh, cbh, acc);
    }
    __syncthreads();  // all waves finished reading X
    float tmp[16];
#pragma unroll
    for (int r = 0; r < 16; ++r) tmp[r] = acc[r];
    storeChl(A0, A1, tmp, R, col, q);  // P' overwrites X
    __syncthreads();
#pragma unroll
    for (int r = 0; r < 16; ++r) acc[r] = 0.0f;
#pragma unroll
    for (int kb = 0; kb < 4; ++kb) {
      bf16x8 cah = readFrag(CtH, kb, q, 32 * R + ln);  // A-op C
      bf16x8 cal = readFrag(CtL, kb, q, 32 * R + ln);
      bf16x8 bph = readFrag(A0, kb, q, col);
      bf16x8 bpl = readFrag(A1, kb, q, col);
      acc = MFMA(cal, bph, acc);
      acc = MFMA(cah, bpl, acc);
      acc = MFMA(cah, bph, acc);
    }
    float* dst = out + (size_t)mat * MSIZE;
#pragma unroll
    for (int r = 0; r < 16; ++r) {
      int row = 32 * R + (r & 3) + 8 * (r >> 2) + 4 * q;
      dst[row * 64 + col] = acc[r];
    }
    __syncthreads();
  }
}

extern "C" void kernel_launch(void* const* d_in, const int* in_sizes, int n_in,
                              void* d_out, int out_size, void* d_ws,
                              size_t ws_size, hipStream_t stream) {
  const float* x = (const float*)d_in[0];
  const float* bias = (const float*)d_in[1];
  float* out = (float*)d_out;
  float* ws = (float*)d_ws;
  const float invB = 1.0f / (float)BATCH;
  float* red1 = out + (size_t)RED1_SLOT * MSIZE;  // 64 stage-1 slots in out

  k1_mean_bias<<<NBLK_RED + 1, 256, 0, stream>>>(x, bias, ws, out);
  k_reduce_parts<<<dim3(4, 32), 256, 0, stream>>>(out, red1, NBLK_RED, 1.0f);
  k_reduce_parts<<<dim3(4, 1), 256, 0, stream>>>(red1, ws + G_OFF, 32, invB);
  k2_mean_ns<<<1, 256, 0, stream>>>(ws);
  k3_logsum_mfma<<<NBLK_K3, 1024, 0, stream>>>(x, ws, out);
  k_reduce_parts<<<dim3(4, 64), 256, 0, stream>>>(out, red1,
                                                  NBLK_K3 * K3_CHAINS, 1.0f);
  k_reduce_parts<<<dim3(4, 1), 256, 0, stream>>>(red1, ws + MBAR_OFF, 64, invB);
  k4_center<<<1, 256, 0, stream>>>(ws);
  k5_out_mfma<<<NBLK_K5, 1024, 0, stream>>>(x, ws, out);
}

// Round 5
// 786.446 us; speedup vs baseline: 1.0119x; 1.0053x over previous
//
#include <hip/hip_runtime.h>

// ---------------------------------------------------------------------------
// SPDBatchNormMean forward, B=8192, n=64, fp32. Eigendecomp-free:
//   G0 = mean(x); Gs/Gis = G0^{±1/2} (Newton-Schulz); M = mean log(Gis x Gis)
//   (deg-18 Chebyshev on [0.3,4.0]); G1 = Gs expm(M) Gs; Gis1 = G1^{-1/2};
//   C = Bs Gis1 (Bs = bias^{1/2}); out = C x C^T.
// Round 7: fix VGPR starvation. Round-6 run confirmed 16 waves/CU (occ 46.6%)
// but the compiler chose 64 VGPRs for the 1024-thread kernels and spilled
// ~60 regs of loop state to scratch (FETCH 354MB, WRITE 91MB = spill
// traffic). __launch_bounds__(1024, 4) = min 4 waves/EU = exactly one
// 16-wave block/CU, raising the VGPR cap to 128 which fits the state.
// Everything else identical to round 6 (single-variable A/B).
// ---------------------------------------------------------------------------

#define BATCH 8192
#define NMAT 64
#define MSIZE 4096
#define NBLK_RED 512
#define NBLK_K3 256
#define K3_CHAINS 4
#define CHAIN_MATS 8
#define NBLK_K5 256
#define DEG 18
#define CHEB_LO 0.30f
#define CHEB_HI 4.00f
#define NS_ITERS_MEAN 10
#define NS_ITERS_BIAS 12
#define GSTR 520 /* padded k-group stride (65*8 elems, 16B-aligned) */

// workspace layout (floats): only the 6 small matrices (96 KB).
#define G_OFF 0
#define BS_OFF (G_OFF + MSIZE)
#define GS_OFF (BS_OFF + MSIZE)
#define GIS_OFF (GS_OFF + MSIZE)
#define MBAR_OFF (GIS_OFF + MSIZE)
#define C_OFF (MBAR_OFF + MSIZE)
// scratch staged in `out` (128 MB, dead until k5): partial slots [0,1024),
// stage-1 reduce slots at [RED1_SLOT, RED1_SLOT+64).
#define RED1_SLOT 2048

typedef __attribute__((ext_vector_type(8))) short bf16x8;
typedef __attribute__((ext_vector_type(16))) float floatx16;
#define MFMA(a, b, c) __builtin_amdgcn_mfma_f32_32x32x16_bf16(a, b, c, 0, 0, 0)

__device__ __forceinline__ short f2bf(float x) {
  union {
    __bf16 b;
    short s;
  } u;
  u.b = (__bf16)x;  // hardware cvt, RNE
  return u.s;
}
__device__ __forceinline__ float bf2f(short h) {
  return __uint_as_float(((unsigned)(unsigned short)h) << 16);
}

// Stage a row-major 64x64 fp32 global matrix M into hi/lo bf16 LDS arrays in
// B-layout holding M^T: arr(k,n) = M[n][k]. 256 threads (st), packed b64.
__device__ __forceinline__ void stageT(const float* __restrict__ src, short* ah,
                                       short* al, int st) {
#pragma unroll
  for (int jb = 0; jb < 4; ++jb) {
    int flat = jb * 1024 + st * 4;
    float4 v = *reinterpret_cast<const float4*>(src + flat);
    int i = flat >> 6;   // row of M
    int j0 = flat & 63;  // col base (multiple of 4)
    int addr = (j0 >> 3) * GSTR + i * 8 + (j0 & 7);
    short4 h, l;
    h.x = f2bf(v.x); l.x = f2bf(v.x - bf2f(h.x));
    h.y = f2bf(v.y); l.y = f2bf(v.y - bf2f(h.y));
    h.z = f2bf(v.z); l.z = f2bf(v.z - bf2f(h.z));
    h.w = f2bf(v.w); l.w = f2bf(v.w - bf2f(h.w));
    *reinterpret_cast<short4*>(ah + addr) = h;
    *reinterpret_cast<short4*>(al + addr) = l;
  }
}

// Fragment read: returns elements j=0..7 at k = kb*16 + q*8 + j, column n.
__device__ __forceinline__ bf16x8 readFrag(const short* a, int kb, int q,
                                           int n) {
  return *reinterpret_cast<const bf16x8*>(a + (kb * 2 + q) * GSTR + n * 8);
}

// Store 16 C/D-layout fp32 regs into B-layout array(s) as bf16 (direct:
// arr(k=row, n=col) = v). Packs 4 consecutive rows per b64 write.
__device__ __forceinline__ void storeChi(short* dh, const float* v, int R,
                                         int col, int q) {
#pragma unroll
  for (int g4 = 0; g4 < 4; ++g4) {
    int addr = (4 * R + g4) * GSTR + col * 8 + 4 * q;
    short4 h;
    h.x = f2bf(v[4 * g4 + 0]);
    h.y = f2bf(v[4 * g4 + 1]);
    h.z = f2bf(v[4 * g4 + 2]);
    h.w = f2bf(v[4 * g4 + 3]);
    *reinterpret_cast<short4*>(dh + addr) = h;
  }
}
__device__ __forceinline__ void storeChl(short* dh, short* dl, const float* v,
                                         int R, int col, int q) {
#pragma unroll
  for (int g4 = 0; g4 < 4; ++g4) {
    int addr = (4 * R + g4) * GSTR + col * 8 + 4 * q;
    short4 h, l;
    float a0 = v[4 * g4 + 0], a1 = v[4 * g4 + 1];
    float a2 = v[4 * g4 + 2], a3 = v[4 * g4 + 3];
    h.x = f2bf(a0); l.x = f2bf(a0 - bf2f(h.x));
    h.y = f2bf(a1); l.y = f2bf(a1 - bf2f(h.y));
    h.z = f2bf(a2); l.z = f2bf(a2 - bf2f(h.z));
    h.w = f2bf(a3); l.w = f2bf(a3 - bf2f(h.w));
    *reinterpret_cast<short4*>(dh + addr) = h;
    *reinterpret_cast<short4*>(dl + addr) = l;
  }
}

// ============================ vector-ALU helpers (k1/k2/k4) ================

__device__ __forceinline__ void mm64T(const float* __restrict__ A,
                                      const float* __restrict__ B, int rt,
                                      int ct, float p[4][4]) {
#pragma unroll
  for (int i = 0; i < 4; ++i)
#pragma unroll
    for (int j = 0; j < 4; ++j) p[i][j] = 0.0f;
#pragma unroll 4
  for (int k = 0; k < NMAT; ++k) {
    float4 a = *reinterpret_cast<const float4*>(A + k * NMAT + rt * 4);
    float4 b = *reinterpret_cast<const float4*>(B + k * NMAT + ct * 4);
    p[0][0] = fmaf(a.x, b.x, p[0][0]);
    p[0][1] = fmaf(a.x, b.y, p[0][1]);
    p[0][2] = fmaf(a.x, b.z, p[0][2]);
    p[0][3] = fmaf(a.x, b.w, p[0][3]);
    p[1][0] = fmaf(a.y, b.x, p[1][0]);
    p[1][1] = fmaf(a.y, b.y, p[1][1]);
    p[1][2] = fmaf(a.y, b.z, p[1][2]);
    p[1][3] = fmaf(a.y, b.w, p[1][3]);
    p[2][0] = fmaf(a.z, b.x, p[2][0]);
    p[2][1] = fmaf(a.z, b.y, p[2][1]);
    p[2][2] = fmaf(a.z, b.z, p[2][2]);
    p[2][3] = fmaf(a.z, b.w, p[2][3]);
    p[3][0] = fmaf(a.w, b.x, p[3][0]);
    p[3][1] = fmaf(a.w, b.y, p[3][1]);
    p[3][2] = fmaf(a.w, b.z, p[3][2]);
    p[3][3] = fmaf(a.w, b.w, p[3][3]);
  }
}

__device__ __forceinline__ void storeTile(float* dst, int rt, int ct,
                                          const float p[4][4]) {
#pragma unroll
  for (int i = 0; i < 4; ++i)
    *reinterpret_cast<float4*>(dst + (rt * 4 + i) * NMAT + ct * 4) =
        make_float4(p[i][0], p[i][1], p[i][2], p[i][3]);
}

__device__ __forceinline__ void loadMat(float* dst,
                                        const float* __restrict__ src,
                                        int tid) {
#pragma unroll
  for (int j = 0; j < 4; ++j)
    *reinterpret_cast<float4*>(dst + j * 1024 + tid * 4) =
        *reinterpret_cast<const float4*>(src + j * 1024 + tid * 4);
}

__device__ __forceinline__ float4 id4(int base) {
  return make_float4(((base + 0) % 65) == 0 ? 1.f : 0.f,
                     ((base + 1) % 65) == 0 ? 1.f : 0.f,
                     ((base + 2) % 65) == 0 ? 1.f : 0.f,
                     ((base + 3) % 65) == 0 ? 1.f : 0.f);
}

__device__ float block_ns(const float* lA, float* lY, float* lZ, float* lW,
                          float* red, int iters) {
  const int tid = threadIdx.x;
  const int rt = tid >> 4, ct = tid & 15;
  float ss = 0.0f;
#pragma unroll
  for (int j = 0; j < 4; ++j) {
    float4 v = *reinterpret_cast<const float4*>(lA + j * 1024 + tid * 4);
    ss += v.x * v.x + v.y * v.y + v.z * v.z + v.w * v.w;
  }
  red[tid] = ss;
  __syncthreads();
  for (int off = 128; off > 0; off >>= 1) {
    if (tid < off) red[tid] += red[tid + off];
    __syncthreads();
  }
  const float c = sqrtf(red[0] * 0.5f);
  const float rc = 1.0f / c;
#pragma unroll
  for (int j = 0; j < 4; ++j) {
    int base = j * 1024 + tid * 4;
    float4 v = *reinterpret_cast<const float4*>(lA + base);
    v.x *= rc;
    v.y *= rc;
    v.z *= rc;
    v.w *= rc;
    *reinterpret_cast<float4*>(lY + base) = v;
    *reinterpret_cast<float4*>(lZ + base) = id4(base);
  }
  __syncthreads();
  for (int it = 0; it < iters; ++it) {
    float p[4][4];
    mm64T(lZ, lY, rt, ct, p);
    float w[4][4];
#pragma unroll
    for (int i = 0; i < 4; ++i)
#pragma unroll
      for (int j = 0; j < 4; ++j)
        w[i][j] = ((rt * 4 + i) == (ct * 4 + j) ? 1.5f : 0.0f) - 0.5f * p[i][j];
    storeTile(lW, rt, ct, w);
    __syncthreads();
    float py[4][4], pz[4][4];
    mm64T(lY, lW, rt, ct, py);
    mm64T(lW, lZ, rt, ct, pz);
    __syncthreads();
    storeTile(lY, rt, ct, py);
    storeTile(lZ, rt, ct, pz);
    __syncthreads();
  }
  return c;
}

// K1: blocks [0,NBLK_RED) partial-sum x into `pg` (out scratch); block
// NBLK_RED does Bs = bias^{1/2}.
__global__ __launch_bounds__(256) void k1_mean_bias(
    const float* __restrict__ x, const float* __restrict__ bias,
    float* __restrict__ ws, float* __restrict__ pg) {
  const int tid = threadIdx.x;
  if (blockIdx.x < NBLK_RED) {
    float acc[16];
#pragma unroll
    for (int j = 0; j < 16; ++j) acc[j] = 0.f;
    for (int i = blockIdx.x; i < BATCH; i += NBLK_RED) {
      const float* src = x + (size_t)i * MSIZE;
#pragma unroll
      for (int j = 0; j < 4; ++j) {
        float4 v = *reinterpret_cast<const float4*>(src + j * 1024 + tid * 4);
        acc[j * 4 + 0] += v.x;
        acc[j * 4 + 1] += v.y;
        acc[j * 4 + 2] += v.z;
        acc[j * 4 + 3] += v.w;
      }
    }
    float* dst = pg + (size_t)blockIdx.x * MSIZE;
#pragma unroll
    for (int j = 0; j < 4; ++j)
      *reinterpret_cast<float4*>(dst + j * 1024 + tid * 4) = make_float4(
          acc[j * 4 + 0], acc[j * 4 + 1], acc[j * 4 + 2], acc[j * 4 + 3]);
  } else {
    __shared__ __align__(16) float lA[MSIZE], lY[MSIZE], lZ[MSIZE], lW[MSIZE];
    __shared__ float red[257];
    loadMat(lA, bias, tid);
    __syncthreads();
    float c = block_ns(lA, lY, lZ, lW, red, NS_ITERS_BIAS);
    float sc = sqrtf(c);
#pragma unroll
    for (int j = 0; j < 4; ++j) {
      int base = j * 1024 + tid * 4;
      float4 v = *reinterpret_cast<const float4*>(lY + base);
      v.x *= sc;
      v.y *= sc;
      v.z *= sc;
      v.w *= sc;
      *reinterpret_cast<float4*>(ws + BS_OFF + base) = v;
    }
  }
}

// Two-stage partial reduce. grid = (4, NY): block (bx, by) sums parts
// p = by, by+NY, ... for its 1 KB element range; writes slot `by` of dst.
__global__ __launch_bounds__(256) void k_reduce_parts(
    const float* __restrict__ src, float* __restrict__ dst, int nparts,
    float scale) {
  int e4 = blockIdx.x * 256 + threadIdx.x;
  float4 acc = make_float4(0.f, 0.f, 0.f, 0.f);
  for (int b = blockIdx.y; b < nparts; b += gridDim.y) {
    float4 v =
        *reinterpret_cast<const float4*>(src + (size_t)b * MSIZE + e4 * 4);
    acc.x += v.x;
    acc.y += v.y;
    acc.z += v.z;
    acc.w += v.w;
  }
  acc.x *= scale;
  acc.y *= scale;
  acc.z *= scale;
  acc.w *= scale;
  *reinterpret_cast<float4*>(dst + (size_t)blockIdx.y * MSIZE + e4 * 4) = acc;
}

__global__ __launch_bounds__(256) void k2_mean_ns(float* __restrict__ ws) {
  __shared__ __align__(16) float lA[MSIZE], lY[MSIZE], lZ[MSIZE], lW[MSIZE];
  __shared__ float red[257];
  const int tid = threadIdx.x;
  loadMat(lA, ws + G_OFF, tid);
  __syncthreads();
  float c = block_ns(lA, lY, lZ, lW, red, NS_ITERS_MEAN);
  float sc = sqrtf(c), rs = 1.0f / sqrtf(c);
#pragma unroll
  for (int j = 0; j < 4; ++j) {
    int base = j * 1024 + tid * 4;
    float4 y = *reinterpret_cast<const float4*>(lY + base);
    float4 z = *reinterpret_cast<const float4*>(lZ + base);
    *reinterpret_cast<float4*>(ws + GS_OFF + base) =
        make_float4(y.x * sc, y.y * sc, y.z * sc, y.w * sc);
    *reinterpret_cast<float4*>(ws + GIS_OFF + base) =
        make_float4(z.x * rs, z.y * rs, z.z * rs, z.w * rs);
  }
}

// ============================ K3: MFMA Chebyshev log-sum ====================
// 1024 threads = 4 independent 4-wave chains; grid 256 (1 block/CU, 16 waves).
// launch_bounds(1024,4): min 4 waves/EU = 1 block/CU -> VGPR cap 128 (the
// default heuristic chose 64 and spilled ~60 regs of loop state to scratch).
// 3 LDS arrays per chain (A0,A1,A2): X/P0/U time-share (A0,A1) with extra
// barriers; recurrence ping-pongs A2 <-> A0 (U cached in registers).
__global__ __launch_bounds__(1024, 4) void k3_logsum_mfma(
    const float* __restrict__ x, const float* __restrict__ ws,
    float* __restrict__ pm) {
  __shared__ __align__(16) short GisH[GSTR * 8], GisL[GSTR * 8];
  __shared__ __align__(16) short SH[K3_CHAINS][3][GSTR * 8];
  const int tid = threadIdx.x;
  const int ch = tid >> 8;   // chain 0..3
  const int ct = tid & 255;  // thread within chain
  const int w4 = ct >> 6;    // wave within chain
  const int R = w4 >> 1, Cb = w4 & 1;
  const int lane = tid & 63;
  const int ln = lane & 31, q = lane >> 5;
  const int col = 32 * Cb + ln;
  short* A0 = SH[ch][0];
  short* A1 = SH[ch][1];
  short* A2 = SH[ch][2];

  const float m = 0.5f * (CHEB_LO + CHEB_HI), hh = 0.5f * (CHEB_HI - CHEB_LO);
  const float invh = 1.0f / hh;
  const float beta = hh / m;
  const float zeta = (1.0f - sqrtf(1.0f - beta * beta)) / beta;
  const float ca0 = logf(m) - log1pf(zeta * zeta);
  const float ca1 = 2.0f * zeta;

  // diagonal index: r_dg = r for which row(r)==col (or -1). row(r) =
  // 32R + (r&3) + 8(r>>2) + 4q.
  int d = col - 32 * R - 4 * q;
  const int r_dg =
      (d >= 0 && d < 32 && (d & 4) == 0) ? ((d >> 3) * 4 + (d & 3)) : -1;

  if (ch == 0) stageT(ws + GIS_OFF, GisH, GisL, ct);
  __syncthreads();

  float Mac[16];
#pragma unroll
  for (int r = 0; r < 16; ++r) Mac[r] = 0.0f;

  for (int it = 0; it < CHAIN_MATS; ++it) {
    const int mat = blockIdx.x * (K3_CHAINS * CHAIN_MATS) + ch * CHAIN_MATS + it;
    stageT(x + (size_t)mat * MSIZE, A0, A1, ct);
    __syncthreads();
    // mm1: P0 = X * Gis   (A = X frags from A0/A1, B = Gis shared)
    floatx16 acc;
#pragma unroll
    for (int r = 0; r < 16; ++r) acc[r] = 0.0f;
#pragma unroll
    for (int kb = 0; kb < 4; ++kb) {
      bf16x8 axh = readFrag(A0, kb, q, 32 * R + ln);
      bf16x8 axl = readFrag(A1, kb, q, 32 * R + ln);
      bf16x8 gbh = readFrag(GisH, kb, q, col);
      bf16x8 gbl = readFrag(GisL, kb, q, col);
      acc = MFMA(axl, gbh, acc);
      acc = MFMA(axh, gbl, acc);
      acc = MFMA(axh, gbh, acc);
    }
    __syncthreads();  // all waves finished reading X from A0/A1
    float tmp[16];
#pragma unroll
    for (int r = 0; r < 16; ++r) tmp[r] = acc[r];
    storeChl(A0, A1, tmp, R, col, q);  // P0 overwrites X
    __syncthreads();
    // mm2: S = Gis * P0 -> U = (S - mI)/h
#pragma unroll
    for (int r = 0; r < 16; ++r) acc[r] = 0.0f;
#pragma unroll
    for (int kb = 0; kb < 4; ++kb) {
      bf16x8 gah = readFrag(GisH, kb, q, 32 * R + ln);
      bf16x8 gal = readFrag(GisL, kb, q, 32 * R + ln);
      bf16x8 bph = readFrag(A0, kb, q, col);
      bf16x8 bpl = readFrag(A1, kb, q, col);
      acc = MFMA(gal, bph, acc);
      acc = MFMA(gah, bpl, acc);
      acc = MFMA(gah, bph, acc);
    }
    float u[16], tm1[16], tm2[16];
#pragma unroll
    for (int r = 0; r < 16; ++r) {
      float dgr = (r == r_dg) ? 1.0f : 0.0f;
      u[r] = (acc[r] - m * dgr) * invh;
      Mac[r] += ca0 * dgr + ca1 * u[r];
      tm1[r] = u[r];
      tm2[r] = dgr;  // T0 = I
    }
    __syncthreads();  // all waves finished reading P0 from A0/A1
    storeChl(A0, A1, u, R, col, q);  // U overwrites P0
    __syncthreads();
    bf16x8 uh[4], ul[4];
#pragma unroll
    for (int kb = 0; kb < 4; ++kb) {  // A-op U via symmetry -> registers
      uh[kb] = readFrag(A0, kb, q, 32 * R + ln);
      ul[kb] = readFrag(A1, kb, q, 32 * R + ln);
    }
    // k = 2: T2 = 2 U*U - I (B-op U from A0/A1, hi/lo)
#pragma unroll
    for (int r = 0; r < 16; ++r) acc[r] = 0.0f;
#pragma unroll
    for (int kb = 0; kb < 4; ++kb) {
      bf16x8 buh = readFrag(A0, kb, q, col);
      bf16x8 bul = readFrag(A1, kb, q, col);
      acc = MFMA(ul[kb], buh, acc);
      acc = MFMA(uh[kb], bul, acc);
      acc = MFMA(uh[kb], buh, acc);
    }
    float zk = zeta * zeta;
    float ak = -zk;  // -2*zk/2
    float t[16];
#pragma unroll
    for (int r = 0; r < 16; ++r) {
      t[r] = 2.0f * acc[r] - tm2[r];  // tm2 == T0 here
      Mac[r] += ak * t[r];
      tm2[r] = tm1[r];
      tm1[r] = t[r];
    }
    storeChi(A2, t, R, col, q);  // T2 -> A2 (A2 idle; no WAR with A0/A1 reads)
    __syncthreads();
    // k = 3..DEG: T_k = 2 U T_{k-1} - T_{k-2}; B-op bf16-only; ping-pong
    // A2 (even T) <-> A0 (odd T). U stays in registers; A0's U copy is dead.
    for (int k = 3; k <= DEG; ++k) {
      short* src = (k & 1) ? A2 : A0;
      short* dst = (k & 1) ? A0 : A2;
#pragma unroll
      for (int r = 0; r < 16; ++r) acc[r] = 0.0f;
#pragma unroll
      for (int kb = 0; kb < 4; ++kb) {
        bf16x8 b = readFrag(src, kb, q, col);
        acc = MFMA(ul[kb], b, acc);
        acc = MFMA(uh[kb], b, acc);
      }
      zk *= -zeta;
      ak = -2.0f * zk / (float)k;
#pragma unroll
      for (int r = 0; r < 16; ++r) {
        t[r] = 2.0f * acc[r] - tm2[r];
        Mac[r] += ak * t[r];
        tm2[r] = tm1[r];
        tm1[r] = t[r];
      }
      if (k < DEG) storeChi(dst, t, R, col, q);
      __syncthreads();
    }
  }
  // per-chain partial (1024 total)
  float* dst = pm + (size_t)(blockIdx.x * K3_CHAINS + ch) * MSIZE;
#pragma unroll
  for (int r = 0; r < 16; ++r) {
    int row = 32 * R + (r & 3) + 8 * (r >> 2) + 4 * q;
    dst[row * 64 + col] = Mac[r];
  }
}

// K4: E = expm(Mbar); G1 = Gs E Gs; Gis1 = sym(G1)^{-1/2}; C = Bs Gis1 -> ws.
__global__ __launch_bounds__(256) void k4_center(float* __restrict__ ws) {
  __shared__ __align__(16) float lA[MSIZE], lY[MSIZE], lZ[MSIZE], lW[MSIZE];
  __shared__ float red[257];
  const int tid = threadIdx.x;
  const int rt = tid >> 4, ct = tid & 15;
  loadMat(lA, ws + MBAR_OFF, tid);
  __syncthreads();
  if (tid == 0) {
    float mu = 0.f;
    for (int i = 0; i < NMAT; ++i) mu += lA[i * 65];
    red[256] = mu * (1.0f / NMAT);
  }
  __syncthreads();
  const float mu = red[256];
  float ss = 0.f;
#pragma unroll
  for (int j = 0; j < 4; ++j) {
    int base = j * 1024 + tid * 4;
    float4 v = *reinterpret_cast<const float4*>(lA + base);
    float4 idm = id4(base);
    v.x -= mu * idm.x;
    v.y -= mu * idm.y;
    v.z -= mu * idm.z;
    v.w -= mu * idm.w;
    ss += v.x * v.x + v.y * v.y + v.z * v.z + v.w * v.w;
    *reinterpret_cast<float4*>(lA + base) = v;
  }
  red[tid] = ss;
  __syncthreads();
  for (int off = 128; off > 0; off >>= 1) {
    if (tid < off) red[tid] += red[tid + off];
    __syncthreads();
  }
  float nrm = sqrtf(red[0]);
  int s = 0;
  while (nrm > 0.25f && s < 12) {
    nrm *= 0.5f;
    s++;
  }
  const float dscale = exp2f((float)-s);
#pragma unroll
  for (int j = 0; j < 4; ++j) {
    int base = j * 1024 + tid * 4;
    float4 v = *reinterpret_cast<const float4*>(lA + base);
    v.x *= dscale;
    v.y *= dscale;
    v.z *= dscale;
    v.w *= dscale;
    *reinterpret_cast<float4*>(lA + base) = v;
    float4 idm = id4(base);
    *reinterpret_cast<float4*>(lY + base) =
        make_float4(idm.x + v.x * 0.125f, idm.y + v.y * 0.125f,
                    idm.z + v.z * 0.125f, idm.w + v.w * 0.125f);
  }
  __syncthreads();
  float p[4][4];
  for (int j = 7; j >= 1; --j) {
    mm64T(lA, lY, rt, ct, p);
    __syncthreads();
    float w[4][4];
    const float rj = 1.0f / (float)j;
#pragma unroll
    for (int i = 0; i < 4; ++i)
#pragma unroll
      for (int jj = 0; jj < 4; ++jj)
        w[i][jj] =
            p[i][jj] * rj + (((rt * 4 + i) == (ct * 4 + jj)) ? 1.0f : 0.0f);
    storeTile(lY, rt, ct, w);
    __syncthreads();
  }
  for (int tq = 0; tq < s; ++tq) {
    mm64T(lY, lY, rt, ct, p);
    __syncthreads();
    storeTile(lY, rt, ct, p);
    __syncthreads();
  }
  const float emu = expf(mu);
#pragma unroll
  for (int j = 0; j < 4; ++j) {
    int base = j * 1024 + tid * 4;
    float4 v = *reinterpret_cast<const float4*>(lY + base);
    v.x *= emu;
    v.y *= emu;
    v.z *= emu;
    v.w *= emu;
    *reinterpret_cast<float4*>(lY + base) = v;
  }
  __syncthreads();
  loadMat(lZ, ws + GS_OFF, tid);
  __syncthreads();
  mm64T(lY, lZ, rt, ct, p);  // E Gs
  __syncthreads();
  storeTile(lW, rt, ct, p);
  __syncthreads();
  mm64T(lZ, lW, rt, ct, p);  // G1 = Gs E Gs
  __syncthreads();
  storeTile(lA, rt, ct, p);
  __syncthreads();
  float qq[4][4];
#pragma unroll
  for (int i = 0; i < 4; ++i)
#pragma unroll
    for (int j = 0; j < 4; ++j)
      qq[i][j] = 0.5f * (p[i][j] + lA[(ct * 4 + j) * NMAT + rt * 4 + i]);
  __syncthreads();
  storeTile(lA, rt, ct, qq);
  __syncthreads();
  float c = block_ns(lA, lY, lZ, lW, red, NS_ITERS_MEAN);
  const float rs = 1.0f / sqrtf(c);
#pragma unroll
  for (int j = 0; j < 4; ++j) {  // Gis1 -> lY
    int base = j * 1024 + tid * 4;
    float4 v = *reinterpret_cast<const float4*>(lZ + base);
    *reinterpret_cast<float4*>(lY + base) =
        make_float4(v.x * rs, v.y * rs, v.z * rs, v.w * rs);
  }
  __syncthreads();
  loadMat(lZ, ws + BS_OFF, tid);
  __syncthreads();
  mm64T(lZ, lY, rt, ct, p);  // C = Bs Gis1
#pragma unroll
  for (int i = 0; i < 4; ++i)
#pragma unroll
    for (int j = 0; j < 4; ++j)
      ws[C_OFF + (rt * 4 + i) * NMAT + ct * 4 + j] = p[i][j];
}

// ============================ K5: out = C X C^T (MFMA) ======================
// 1024 threads = 4 chains, grid 256 (1 block/CU, 16 waves), VGPR cap 128.
// C^T staged once per block into a shared LDS pair. 2 LDS arrays per chain:
// X then P' time-share (A0,A1) with one extra barrier.
// mm1: P' = X*C^T (A = X frags, B = C^T frags); mm2: O = C*P'.
__global__ __launch_bounds__(1024, 4) void k5_out_mfma(
    const float* __restrict__ x, const float* __restrict__ ws,
    float* __restrict__ out) {
  __shared__ __align__(16) short CtH[GSTR * 8], CtL[GSTR * 8];
  __shared__ __align__(16) short SH[K3_CHAINS][2][GSTR * 8];
  const int tid = threadIdx.x;
  const int ch = tid >> 8;
  const int ct = tid & 255;
  const int w4 = ct >> 6;
  const int R = w4 >> 1, Cb = w4 & 1;
  const int lane = tid & 63;
  const int ln = lane & 31, q = lane >> 5;
  const int col = 32 * Cb + ln;
  short* A0 = SH[ch][0];
  short* A1 = SH[ch][1];

  if (ch == 0) stageT(ws + C_OFF, CtH, CtL, ct);  // arr(k,n) = C[n][k]
  __syncthreads();

  for (int it = 0; it < CHAIN_MATS; ++it) {
    const int mat = blockIdx.x * (K3_CHAINS * CHAIN_MATS) + ch * CHAIN_MATS + it;
    stageT(x + (size_t)mat * MSIZE, A0, A1, ct);
    __syncthreads();
    floatx16 acc;
#pragma unroll
    for (int r = 0; r < 16; ++r) acc[r] = 0.0f;
#pragma unroll
    for (int kb = 0; kb < 4; ++kb) {
      bf16x8 axh = readFrag(A0, kb, q, 32 * R + ln);
      bf16x8 axl = readFrag(A1, kb, q, 32 * R + ln);
      bf16x8 cbh = readFrag(CtH, kb, q, col);  // B-op C^T
      bf16x8 cbl = readFrag(CtL, kb, q, col);
      acc = MFMA(axl, cbh, acc);
      acc = MFMA(axh, cbl, acc);
      acc = MFMA(axh, cbh, acc);
    }
    __syncthreads();  // all waves finished reading X
    float tmp[16];
#pragma unroll
    for (int r = 0; r < 16; ++r) tmp[r] = acc[r];
    storeChl(A0, A1, tmp, R, col, q);  // P' overwrites X
    __syncthreads();
#pragma unroll
    for (int r = 0; r < 16; ++r) acc[r] = 0.0f;
#pragma unroll
    for (int kb = 0; kb < 4; ++kb) {
      bf16x8 cah = readFrag(CtH, kb, q, 32 * R + ln);  // A-op C
      bf16x8 cal = readFrag(CtL, kb, q, 32 * R + ln);
      bf16x8 bph = readFrag(A0, kb, q, col);
      bf16x8 bpl = readFrag(A1, kb, q, col);
      acc = MFMA(cal, bph, acc);
      acc = MFMA(cah, bpl, acc);
      acc = MFMA(cah, bph, acc);
    }
    float* dst = out + (size_t)mat * MSIZE;
#pragma unroll
    for (int r = 0; r < 16; ++r) {
      int row = 32 * R + (r & 3) + 8 * (r >> 2) + 4 * q;
      dst[row * 64 + col] = acc[r];
    }
    __syncthreads();
  }
}

extern "C" void kernel_launch(void* const* d_in, const int* in_sizes, int n_in,
                              void* d_out, int out_size, void* d_ws,
                              size_t ws_size, hipStream_t stream) {
  const float* x = (const float*)d_in[0];
  const float* bias = (const float*)d_in[1];
  float* out = (float*)d_out;
  float* ws = (float*)d_ws;
  const float invB = 1.0f / (float)BATCH;
  float* red1 = out + (size_t)RED1_SLOT * MSIZE;  // 64 stage-1 slots in out

  k1_mean_bias<<<NBLK_RED + 1, 256, 0, stream>>>(x, bias, ws, out);
  k_reduce_parts<<<dim3(4, 32), 256, 0, stream>>>(out, red1, NBLK_RED, 1.0f);
  k_reduce_parts<<<dim3(4, 1), 256, 0, stream>>>(red1, ws + G_OFF, 32, invB);
  k2_mean_ns<<<1, 256, 0, stream>>>(ws);
  k3_logsum_mfma<<<NBLK_K3, 1024, 0, stream>>>(x, ws, out);
  k_reduce_parts<<<dim3(4, 64), 256, 0, stream>>>(out, red1,
                                                  NBLK_K3 * K3_CHAINS, 1.0f);
  k_reduce_parts<<<dim3(4, 1), 256, 0, stream>>>(red1, ws + MBAR_OFF, 64, invB);
  k4_center<<<1, 256, 0, stream>>>(ws);
  k5_out_mfma<<<NBLK_K5, 1024, 0, stream>>>(x, ws, out);
}